// Round 5
// baseline (322.057 us; speedup 1.0000x reference)
//
#include <hip/hip_runtime.h>
#include <hip/hip_bf16.h>
#include <stdint.h>

// NBEATS MoE block — round 9: persistent-B blocks, barrier-free K-loop.
// Rounds 4/5/7/8 all landed 46-54us per gemm dispatch regardless of tile,
// BK, occupancy, pipelining: the shared constant was the barrier-coupled
// per-K-step stage/wait cycle (~7000cy per step measured from block-pass
// arithmetic). This round removes it:
//   - block = (expert e, 256-row range, 64-col panel). B panel for FULL
//     K=512 is 64KB -> staged into LDS ONCE (gload_lds, linear dest +
//     pre-swizzled src, XOR read = verified conflict-free), one
//     __syncthreads, then ZERO barriers afterward.
//   - each wave independently: 64 rows x 64 cols, per k-chunk
//     {4 A global->VGPR, 4 B ds_read, 16 MFMA} x 16 chunks, unrolled;
//     compiler emits counted waitcnts; waves never couple.
//   - grid (8,9,8) x-fastest => expert e pinned to XCD e: weights and z
//     rows stay in one XCD's L2 (r7 showed FETCH 36->11MB from this).
//   - staged-LDS bytes 295->37MB/dispatch; A streams via L2.
// gate/assign/transpose unchanged.

#define B_ROWS 8192
#define I_DIM  512
#define H_DIM  512
#define E_NUM  8
#define T_DIM  608
#define T_PAD  640
#define CAP    2304   // rows per expert segment (capacity)
#define NPAD   18432  // CAP*E_NUM

typedef unsigned short ushort_t;
typedef __attribute__((ext_vector_type(8))) __bf16 bf16x8;
typedef __attribute__((ext_vector_type(8))) unsigned short ushort8;
typedef __attribute__((ext_vector_type(4))) float floatx4;

__device__ __forceinline__ void gload_lds16(const void* g, void* l) {
  __builtin_amdgcn_global_load_lds(
      (const __attribute__((address_space(1))) unsigned int*)g,
      (__attribute__((address_space(3))) unsigned int*)l, 16, 0, 0);
}

__device__ __forceinline__ ushort_t f2bf(float v) {
  __hip_bfloat16 h = __float2bfloat16(v);
  return __builtin_bit_cast(unsigned short, h);
}

// ---------------------------------------------------------------- gating ----
__global__ __launch_bounds__(256) void gate_cast_k(
    const float* __restrict__ x, const float* __restrict__ gamma,
    const float* __restrict__ beta, const float* __restrict__ Wg,
    ushort_t* __restrict__ xb, int2* __restrict__ gidx, float2* __restrict__ gw)
{
  const int row  = (blockIdx.x * blockDim.x + threadIdx.x) >> 6;
  const int lane = threadIdx.x & 63;
  const float* xr = x + (size_t)row * I_DIM + lane * 8;
  float4 a = *(const float4*)(xr);
  float4 b = *(const float4*)(xr + 4);
  float xs[8] = {a.x, a.y, a.z, a.w, b.x, b.y, b.z, b.w};

  float s = 0.f;
#pragma unroll
  for (int j = 0; j < 8; ++j) s += xs[j];
#pragma unroll
  for (int off = 32; off; off >>= 1) s += __shfl_xor(s, off);
  const float mu = s * (1.0f / I_DIM);

  float vs = 0.f;
#pragma unroll
  for (int j = 0; j < 8; ++j) { float d = xs[j] - mu; vs += d * d; }
#pragma unroll
  for (int off = 32; off; off >>= 1) vs += __shfl_xor(vs, off);
  const float rstd = rsqrtf(vs * (1.0f / I_DIM) + 1e-5f);

  float lg[8] = {0.f, 0.f, 0.f, 0.f, 0.f, 0.f, 0.f, 0.f};
  const float* gmr = gamma + lane * 8;
  const float* btr = beta + lane * 8;
#pragma unroll
  for (int j = 0; j < 8; ++j) {
    const float y = (xs[j] - mu) * rstd * gmr[j] + btr[j];
    const float* wr = Wg + (size_t)(lane * 8 + j) * E_NUM;
#pragma unroll
    for (int e = 0; e < 8; ++e) lg[e] += y * wr[e];
  }
#pragma unroll
  for (int e = 0; e < 8; ++e)
#pragma unroll
    for (int off = 32; off; off >>= 1) lg[e] += __shfl_xor(lg[e], off);

  ushort8 o;
#pragma unroll
  for (int j = 0; j < 8; ++j) o[j] = f2bf(xs[j]);
  *(ushort8*)(xb + (size_t)row * I_DIM + lane * 8) = o;

  if (lane == 0) {
    int i0 = 0; float b0 = lg[0];
#pragma unroll
    for (int e = 1; e < 8; ++e) if (lg[e] > b0) { b0 = lg[e]; i0 = e; }
    int i1 = -1; float b1 = -3.4e38f;
#pragma unroll
    for (int e = 0; e < 8; ++e) if (e != i0 && lg[e] > b1) { b1 = lg[e]; i1 = e; }
    const float w0 = 1.0f / (1.0f + __expf(b1 - b0));
    gidx[row] = make_int2(i0, i1);
    gw[row] = make_float2(w0, 1.0f - w0);
  }
}

// ------------------------------------------------------------ assignment ----
__global__ __launch_bounds__(256) void assign_k(
    const int2* __restrict__ gidx, const float2* __restrict__ gw,
    int* __restrict__ rowmap, float* __restrict__ wmap,
    int* __restrict__ cursor)
{
  __shared__ int lcnt[E_NUM];
  __shared__ int lbase[E_NUM];
  const int tid = threadIdx.x;
  const int row = blockIdx.x * 256 + tid;
  if (tid < E_NUM) lcnt[tid] = 0;
  __syncthreads();
  const int2 g = gidx[row];
  const float2 w = gw[row];
  const int r0 = atomicAdd(&lcnt[g.x], 1);
  const int r1 = atomicAdd(&lcnt[g.y], 1);
  __syncthreads();
  if (tid < E_NUM) lbase[tid] = atomicAdd(&cursor[tid], lcnt[tid]);
  __syncthreads();
  const int p0 = g.x * CAP + lbase[g.x] + r0;
  rowmap[p0] = row; wmap[p0] = w.x;
  const int p1 = g.y * CAP + lbase[g.y] + r1;
  rowmap[p1] = row; wmap[p1] = w.y;
}

// ------------------------------------------------- weight transpose+cast ----
__global__ __launch_bounds__(256) void transpose_cast_k(
    const float* __restrict__ src, ushort_t* __restrict__ dst,
    int R, int C, size_t srcBStr, size_t dstBStr)
{
  __shared__ float tile[32][33];
  src += (size_t)blockIdx.z * srcBStr;
  dst += (size_t)blockIdx.z * dstBStr;
  const int c0 = blockIdx.x * 32, r0 = blockIdx.y * 32;
  const int tx = threadIdx.x, ty = threadIdx.y;
#pragma unroll
  for (int i = 0; i < 4; ++i)
    tile[ty + i * 8][tx] = src[(size_t)(r0 + ty + i * 8) * C + c0 + tx];
  __syncthreads();
#pragma unroll
  for (int i = 0; i < 4; ++i) {
    const int c = c0 + ty + i * 8;
    if (c < C) dst[(size_t)c * R + r0 + tx] = f2bf(tile[tx][ty + i * 8]);
  }
}

// ------------------------------------------------------------------ GEMM ----
// Persistent-B: block (e, m9, n-panel). B [64 cols][512 k] bf16 in LDS once,
// XOR-swizzled (byte X of col c stored at X ^ ((c&7)<<4); 2 lanes/bank on
// read = free). Then barrier-free: each wave computes 64 rows x 64 cols.
template <bool GATHER, bool RELU, bool FINAL>
__global__ __launch_bounds__(256, 2) void gemm_k(
    const ushort_t* __restrict__ A,      // GATHER: xb [8192][512]; else z [NPAD][512]
    const ushort_t* __restrict__ B,      // bf16 [E][N][512]
    size_t bEStr,
    const int* __restrict__ rowmap, const float* __restrict__ wmap,
    const int* __restrict__ cursor,      // live counts per expert
    ushort_t* __restrict__ Z,            // mid out [NPAD][512]
    float* __restrict__ out)             // final out (split)
{
  __shared__ char lB[64 * 1024];         // 64 cols x 1KB (full K), swizzled

  const int e  = blockIdx.x;             // expert; x fastest -> XCD e
  const int m9 = blockIdx.y;             // 256-row range in segment
  const int n0 = blockIdx.z * 64;        // col panel
  const int cnt = cursor[e];
  if (m9 * 256 >= cnt) return;           // dead block (uniform)
  const int zr0 = e * CAP;

  const int tid = threadIdx.x, wid = tid >> 6, lane = tid & 63;
  const int fr = lane & 15, q = lane >> 4;

  // ---- stage B panel once: wave-instr j stages column wid*16+j (1KB) ----
  // LDS dest linear (base + lane*16, gload_lds constraint); source byte
  // pre-swizzled by the same involution used on the read side.
  const ushort_t* Bb = B + (size_t)e * bEStr + (size_t)n0 * 512;
#pragma unroll
  for (int j = 0; j < 16; ++j) {
    const int col = wid * 16 + j;
    const int sb = (lane * 16) ^ ((col & 7) << 4);  // src byte within col
    gload_lds16((const char*)(Bb + (size_t)col * 512) + sb,
                lB + col * 1024 + lane * 16);
  }
  __syncthreads();   // only barrier in the kernel (drains vmcnt)

  // ---- this wave's 64 rows ----
  const int r0 = m9 * 256 + wid * 64;    // row offset within segment
  if (r0 >= cnt) return;                 // dead wave (after barrier: safe)

  const ushort_t* ga[4];
#pragma unroll
  for (int s2 = 0; s2 < 4; ++s2) {
    const int slot = zr0 + r0 + s2 * 16 + fr;
    const int ar = GATHER ? rowmap[slot] : slot;
    ga[s2] = A + (size_t)ar * 512 + q * 8;
  }

  floatx4 acc[4][4] = {};                // [row-block s2][col-block ni]
#pragma unroll
  for (int c = 0; c < 16; ++c) {         // k-chunk of 32 elems
    bf16x8 bfv[4];
#pragma unroll
    for (int ni = 0; ni < 4; ++ni) {
      const int col = ni * 16 + fr;
      bfv[ni] = *(const bf16x8*)(
          lB + col * 1024 + ((c * 64 + q * 16) ^ ((col & 7) << 4)));
    }
#pragma unroll
    for (int s2 = 0; s2 < 4; ++s2) {
      const bf16x8 af = *(const bf16x8*)(ga[s2] + c * 32);
#pragma unroll
      for (int ni = 0; ni < 4; ++ni)
        acc[s2][ni] = __builtin_amdgcn_mfma_f32_16x16x32_bf16(
            af, bfv[ni], acc[s2][ni], 0, 0, 0);
    }
  }

  // ---- epilogue ----
  // C/D: D row = (A-block) + q*4 + reg, D col = (B-block) + fr (m89)
  if (!FINAL) {
#pragma unroll
    for (int s2 = 0; s2 < 4; ++s2)
#pragma unroll
      for (int r = 0; r < 4; ++r) {
        const int slot = zr0 + r0 + s2 * 16 + q * 4 + r;
        ushort_t* zrp = Z + (size_t)slot * H_DIM + n0 + fr;
#pragma unroll
        for (int ni = 0; ni < 4; ++ni) {
          float v = acc[s2][ni][r];
          if (RELU) v = fmaxf(v, 0.0f);
          zrp[ni * 16] = f2bf(v);
        }
      }
  } else {
#pragma unroll
    for (int s2 = 0; s2 < 4; ++s2)
#pragma unroll
      for (int r = 0; r < 4; ++r) {
        const int slot = zr0 + r0 + s2 * 16 + q * 4 + r;
        const float w = wmap[slot];
        if (w != 0.0f) {
          const size_t orig = rowmap[slot];
#pragma unroll
          for (int ni = 0; ni < 4; ++ni) {
            const int col = n0 + ni * 16 + fr;
            if (col < T_DIM) {
              const float v = acc[s2][ni][r] * w;
              float* dst = (col < I_DIM)
                  ? out + orig * I_DIM + col
                  : out + (size_t)B_ROWS * I_DIM + orig * (T_DIM - I_DIM) +
                        (col - I_DIM);
              atomicAdd(dst, v);
            }
          }
        }
      }
  }
}

// ---------------------------------------------------------------- launch ----
extern "C" void kernel_launch(void* const* d_in, const int* in_sizes, int n_in,
                              void* d_out, int out_size, void* d_ws,
                              size_t ws_size, hipStream_t stream) {
  const float* x     = (const float*)d_in[0];
  const float* gamma = (const float*)d_in[1];
  const float* beta  = (const float*)d_in[2];
  const float* Wg    = (const float*)d_in[3];
  const float* W0    = (const float*)d_in[4];
  const float* Wmid  = (const float*)d_in[5];
  const float* Wout  = (const float*)d_in[6];
  float* out = (float*)d_out;

  char* ws = (char*)d_ws;
  size_t off = 0;
  auto alloc = [&](size_t bytes) -> char* {
    char* p = ws + off;
    off += (bytes + 255) & ~(size_t)255;
    return p;
  };

  const size_t SQ = (size_t)H_DIM * H_DIM;
  ushort_t* xb    = (ushort_t*)alloc((size_t)B_ROWS * I_DIM * 2);
  ushort_t* W0t   = (ushort_t*)alloc((size_t)E_NUM * SQ * 2);
  ushort_t* Wmidt = (ushort_t*)alloc((size_t)3 * E_NUM * SQ * 2);
  ushort_t* Woutt = (ushort_t*)alloc((size_t)E_NUM * T_PAD * H_DIM * 2);
  int2*   gidx  = (int2*)alloc((size_t)B_ROWS * sizeof(int2));
  float2* gwv   = (float2*)alloc((size_t)B_ROWS * sizeof(float2));
  int*   rmap   = (int*)alloc(NPAD * sizeof(int));
  float* wmap   = (float*)alloc(NPAD * sizeof(float));
  int*   cursor = (int*)alloc(E_NUM * sizeof(int));
  ushort_t* z0 = (ushort_t*)alloc((size_t)NPAD * H_DIM * 2);
  ushort_t* z1 = (ushort_t*)alloc((size_t)NPAD * H_DIM * 2);

  hipMemsetAsync(d_out, 0, (size_t)out_size * sizeof(float), stream);
  hipMemsetAsync(rmap, 0, NPAD * sizeof(int), stream);
  hipMemsetAsync(wmap, 0, NPAD * sizeof(float), stream);
  hipMemsetAsync(cursor, 0, E_NUM * sizeof(int), stream);

  gate_cast_k<<<dim3(B_ROWS / 4), 256, 0, stream>>>(x, gamma, beta, Wg, xb,
                                                    gidx, gwv);
  transpose_cast_k<<<dim3(16, 16, 8), dim3(32, 8), 0, stream>>>(
      W0, W0t, 512, 512, SQ, SQ);
  transpose_cast_k<<<dim3(16, 16, 24), dim3(32, 8), 0, stream>>>(
      Wmid, Wmidt, 512, 512, SQ, SQ);
  transpose_cast_k<<<dim3(19, 16, 8), dim3(32, 8), 0, stream>>>(
      Wout, Woutt, 512, 608, (size_t)512 * 608, (size_t)T_PAD * 512);
  assign_k<<<dim3(B_ROWS / 256), 256, 0, stream>>>(gidx, gwv, rmap, wmap,
                                                   cursor);

  const dim3 gmid(E_NUM, CAP / 256, H_DIM / 64);   // (8, 9, 8)
  const dim3 gfin(E_NUM, CAP / 256, T_PAD / 64);   // (8, 9, 10)
  // z0 = gather(x) @ W0   (no relu)
  gemm_k<true, false, false><<<gmid, 256, 0, stream>>>(
      xb, W0t, SQ, rmap, wmap, cursor, z0, nullptr);
  // z1 = relu(z0 @ Wmid[0])
  gemm_k<false, true, false><<<gmid, 256, 0, stream>>>(
      z0, Wmidt + 0 * E_NUM * SQ, SQ, rmap, wmap, cursor, z1, nullptr);
  // z0 = relu(z1 @ Wmid[1])
  gemm_k<false, true, false><<<gmid, 256, 0, stream>>>(
      z1, Wmidt + 1 * E_NUM * SQ, SQ, rmap, wmap, cursor, z0, nullptr);
  // z1 = relu(z0 @ Wmid[2])
  gemm_k<false, true, false><<<gmid, 256, 0, stream>>>(
      z0, Wmidt + 2 * E_NUM * SQ, SQ, rmap, wmap, cursor, z1, nullptr);
  // out += gate_w * (z1 @ Wout), scattered + split backcast/forecast
  gemm_k<false, false, true><<<gfin, 256, 0, stream>>>(
      z1, Woutt, (size_t)T_PAD * H_DIM, rmap, wmap, cursor, nullptr, out);
}

// Round 8
// 257.046 us; speedup vs baseline: 1.2529x; 1.2529x over previous
//
#include <hip/hip_runtime.h>
#include <hip/hip_bf16.h>
#include <stdint.h>

// NBEATS MoE block — round 12: K-loop race fixed at the root + coalesced
// z-epilogue.
// r10/r11 failed nondeterministically (~2.5e-3) with the SAME magnitude
// despite r11's epilogue fence -> the race is in the K-LOOP: stage(s+1)
// DMA-writes buf[(s+1)&1], whose last readers were step s-1's ds_reads.
// Those reads were issued before the step-(s-1) trailing barrier, but raw
// s_barrier does NOT drain counters, and hipcc may sink register-only MFMAs
// (and their lgkmcnt waits) past inline-asm+barrier (rule #18). A lagging
// wave can cross with ds_reads still in the LDS pipe while another wave's
// DMA lands in that buffer. Latent in r7 (scheduling luck); exposed by the
// r10 epilogue's codegen perturbation (rule #19).
// FIX: per-step sync is a full __syncthreads() — drains each wave's own
// vmcnt AND lgkmcnt before the barrier + compiler fence. Its vmcnt wait is
// what r7's asm already did at the same point, so perf ≈ r7.
// Epilogue hypothesis under test (unchanged from r10/r11): WRITE_SIZE was
// pinned at 38912KB = 2.06x the 18.9MB z payload across r4-r9 (scattered 2B
// stores, partial-sector writeback). Coalesced LDS-transpose epilogue ->
// quarter-wave-contiguous 16B stores.

#define B_ROWS 8192
#define I_DIM  512
#define H_DIM  512
#define E_NUM  8
#define T_DIM  608
#define T_PAD  640
#define CAP    2304   // rows per expert segment (capacity)
#define TPW    36     // 64-row tiles per expert = CAP/64
#define MT     288    // M-tiles total = E_NUM*TPW
#define NPAD   18432  // CAP*E_NUM

typedef unsigned short ushort_t;
typedef __attribute__((ext_vector_type(8))) __bf16 bf16x8;
typedef __attribute__((ext_vector_type(8))) unsigned short ushort8;
typedef __attribute__((ext_vector_type(4))) float floatx4;

__device__ __forceinline__ void gload_lds16(const void* g, void* l) {
  __builtin_amdgcn_global_load_lds(
      (const __attribute__((address_space(1))) unsigned int*)g,
      (__attribute__((address_space(3))) unsigned int*)l, 16, 0, 0);
}

__device__ __forceinline__ ushort_t f2bf(float v) {
  __hip_bfloat16 h = __float2bfloat16(v);
  return __builtin_bit_cast(unsigned short, h);
}

// ---------------------------------------------------------------- gating ----
__global__ __launch_bounds__(256) void gate_cast_k(
    const float* __restrict__ x, const float* __restrict__ gamma,
    const float* __restrict__ beta, const float* __restrict__ Wg,
    ushort_t* __restrict__ xb, int2* __restrict__ gidx, float2* __restrict__ gw)
{
  const int row  = (blockIdx.x * blockDim.x + threadIdx.x) >> 6;
  const int lane = threadIdx.x & 63;
  const float* xr = x + (size_t)row * I_DIM + lane * 8;
  float4 a = *(const float4*)(xr);
  float4 b = *(const float4*)(xr + 4);
  float xs[8] = {a.x, a.y, a.z, a.w, b.x, b.y, b.z, b.w};

  float s = 0.f;
#pragma unroll
  for (int j = 0; j < 8; ++j) s += xs[j];
#pragma unroll
  for (int off = 32; off; off >>= 1) s += __shfl_xor(s, off);
  const float mu = s * (1.0f / I_DIM);

  float vs = 0.f;
#pragma unroll
  for (int j = 0; j < 8; ++j) { float d = xs[j] - mu; vs += d * d; }
#pragma unroll
  for (int off = 32; off; off >>= 1) vs += __shfl_xor(vs, off);
  const float rstd = rsqrtf(vs * (1.0f / I_DIM) + 1e-5f);

  float lg[8] = {0.f, 0.f, 0.f, 0.f, 0.f, 0.f, 0.f, 0.f};
  const float* gmr = gamma + lane * 8;
  const float* btr = beta + lane * 8;
#pragma unroll
  for (int j = 0; j < 8; ++j) {
    const float y = (xs[j] - mu) * rstd * gmr[j] + btr[j];
    const float* wr = Wg + (size_t)(lane * 8 + j) * E_NUM;
#pragma unroll
    for (int e = 0; e < 8; ++e) lg[e] += y * wr[e];
  }
#pragma unroll
  for (int e = 0; e < 8; ++e)
#pragma unroll
    for (int off = 32; off; off >>= 1) lg[e] += __shfl_xor(lg[e], off);

  ushort8 o;
#pragma unroll
  for (int j = 0; j < 8; ++j) o[j] = f2bf(xs[j]);
  *(ushort8*)(xb + (size_t)row * I_DIM + lane * 8) = o;

  if (lane == 0) {
    int i0 = 0; float b0 = lg[0];
#pragma unroll
    for (int e = 1; e < 8; ++e) if (lg[e] > b0) { b0 = lg[e]; i0 = e; }
    int i1 = -1; float b1 = -3.4e38f;
#pragma unroll
    for (int e = 0; e < 8; ++e) if (e != i0 && lg[e] > b1) { b1 = lg[e]; i1 = e; }
    const float w0 = 1.0f / (1.0f + __expf(b1 - b0));
    gidx[row] = make_int2(i0, i1);
    gw[row] = make_float2(w0, 1.0f - w0);
  }
}

// ------------------------------------------------------------ assignment ----
__global__ __launch_bounds__(256) void assign_k(
    const int2* __restrict__ gidx, const float2* __restrict__ gw,
    int* __restrict__ rowmap, float* __restrict__ wmap,
    int* __restrict__ cursor)
{
  __shared__ int lcnt[E_NUM];
  __shared__ int lbase[E_NUM];
  const int tid = threadIdx.x;
  const int row = blockIdx.x * 256 + tid;
  if (tid < E_NUM) lcnt[tid] = 0;
  __syncthreads();
  const int2 g = gidx[row];
  const float2 w = gw[row];
  const int r0 = atomicAdd(&lcnt[g.x], 1);
  const int r1 = atomicAdd(&lcnt[g.y], 1);
  __syncthreads();
  if (tid < E_NUM) lbase[tid] = atomicAdd(&cursor[tid], lcnt[tid]);
  __syncthreads();
  const int p0 = g.x * CAP + lbase[g.x] + r0;
  rowmap[p0] = row; wmap[p0] = w.x;
  const int p1 = g.y * CAP + lbase[g.y] + r1;
  rowmap[p1] = row; wmap[p1] = w.y;
}

// ------------------------------------------------- weight transpose+cast ----
__global__ __launch_bounds__(256) void transpose_cast_k(
    const float* __restrict__ src, ushort_t* __restrict__ dst,
    int R, int C, size_t srcBStr, size_t dstBStr)
{
  __shared__ float tile[32][33];
  src += (size_t)blockIdx.z * srcBStr;
  dst += (size_t)blockIdx.z * dstBStr;
  const int c0 = blockIdx.x * 32, r0 = blockIdx.y * 32;
  const int tx = threadIdx.x, ty = threadIdx.y;
#pragma unroll
  for (int i = 0; i < 4; ++i)
    tile[ty + i * 8][tx] = src[(size_t)(r0 + ty + i * 8) * C + c0 + tx];
  __syncthreads();
#pragma unroll
  for (int i = 0; i < 4; ++i) {
    const int c = c0 + ty + i * 8;
    if (c < C) dst[(size_t)c * R + r0 + tx] = f2bf(tile[tx][ty + i * 8]);
  }
}

// ------------------------------------------------------------------ GEMM ----
// 64x128 tile, 4 waves (2M x 2N), BK=64, 2-phase double-buffer, swizzled.
// blockIdx.x = M-tile t: expert e = t&7 (XCD-affine), lt = t>>3,
// slot rows zr0 = e*CAP + lt*64.  blockIdx.y = 128-col N panel.
template <bool GATHER, bool RELU, bool FINAL>
__global__ __launch_bounds__(256, 3) void gemm_k(
    const ushort_t* __restrict__ A,      // GATHER: xb [8192][K]; else z [NPAD][K]
    const ushort_t* __restrict__ B,      // bf16 [E][N][K]
    size_t bEStr,
    const int* __restrict__ rowmap, const float* __restrict__ wmap,
    const int* __restrict__ cursor,      // live counts per expert
    ushort_t* __restrict__ Z,            // mid out [NPAD][H_DIM]
    float* __restrict__ out)             // final out (split)
{
  constexpr int K = 512;
  constexpr int BK = 64;                 // elems per K-step (128B rows)
  constexpr int NSTEP = K / BK;          // 8
  __shared__ char lA[2][64 * 128];       // 2 x 8KB
  __shared__ char lB[2][128 * 128];      // 2 x 16KB
  __shared__ float wrow[64];
  __shared__ int rrow[64];

  const int t = blockIdx.x;
  const int e = t & 7;                   // XCD-affine expert mapping
  const int lt = t >> 3;
  if (lt * 64 >= cursor[e]) return;      // dead (all-pad) tile
  const int zr0 = e * CAP + lt * 64;
  const int bn0 = blockIdx.y * 128;

  const int tid = threadIdx.x, wid = tid >> 6, lane = tid & 63;
  // staging decomposition: thread -> (row-in-32-group, 16B k-slot)
  const int sr = tid >> 3;               // 0..31
  const int sk = tid & 7;                // 0..7

  const ushort_t* Bb = B + (size_t)e * bEStr + (size_t)bn0 * K;
  const ushort_t* gA[2];
  const ushort_t* gB[4];
#pragma unroll
  for (int p = 0; p < 2; ++p) {
    const int r = p * 32 + sr;
    int grow;
    if (GATHER) grow = rowmap[zr0 + r];
    else        grow = zr0 + r;
    gA[p] = A + (size_t)grow * K + ((sk ^ (r & 7)) * 8);   // pre-swizzled src
  }
#pragma unroll
  for (int p = 0; p < 4; ++p) {
    const int r = p * 32 + sr;
    gB[p] = Bb + (size_t)r * K + ((sk ^ (r & 7)) * 8);
  }

  auto stage = [&](int tt) {
    char* da = lA[tt & 1];
    char* db = lB[tt & 1];
    const int k0 = tt * BK;
#pragma unroll
    for (int p = 0; p < 2; ++p)
      gload_lds16(gA[p] + k0, da + (p * 32 + sr) * 128 + sk * 16);
#pragma unroll
    for (int p = 0; p < 4; ++p)
      gload_lds16(gB[p] + k0, db + (p * 32 + sr) * 128 + sk * 16);
  };

  floatx4 acc[2][4] = {};
  const int wm = (wid >> 1) * 32, wn = (wid & 1) * 64;
  const int fr = lane & 15, q = lane >> 4;

  stage(0);
  __syncthreads();   // full drain: DMA complete, fence (r12 race fix)

#pragma unroll
  for (int step = 0; step < NSTEP; ++step) {
    const int cur = step & 1;
    if (step < NSTEP - 1) stage(step + 1);   // next tile in flight under MFMA

    bf16x8 af[2][2], bfr[4][2];
    const char* bA = lA[cur];
    const char* bB = lB[cur];
#pragma unroll
    for (int mi = 0; mi < 2; ++mi) {
      const int row = wm + mi * 16 + fr;
      const int rb = row * 128, rx = (row & 7) << 4;
#pragma unroll
      for (int kk = 0; kk < 2; ++kk)
        af[mi][kk] = *(const bf16x8*)(bA + ((rb + kk * 64 + q * 16) ^ rx));
    }
#pragma unroll
    for (int ni = 0; ni < 4; ++ni) {
      const int row = wn + ni * 16 + fr;
      const int rb = row * 128, rx = (row & 7) << 4;
#pragma unroll
      for (int kk = 0; kk < 2; ++kk)
        bfr[ni][kk] = *(const bf16x8*)(bB + ((rb + kk * 64 + q * 16) ^ rx));
    }
#pragma unroll
    for (int kk = 0; kk < 2; ++kk)
#pragma unroll
      for (int mi = 0; mi < 2; ++mi)
#pragma unroll
        for (int ni = 0; ni < 4; ++ni)
          acc[mi][ni] = __builtin_amdgcn_mfma_f32_16x16x32_bf16(
              af[mi][kk], bfr[ni][kk], acc[mi][ni], 0, 0, 0);

    if (step < NSTEP - 1) {
      // r12 race fix: __syncthreads (NOT asm vmcnt + raw s_barrier).
      // Drains this wave's lgkmcnt to 0 BEFORE the barrier, so no wave can
      // cross with ds_reads still in the LDS pipe while the next step's
      // DMA overwrites their source buffer (rule #18: raw barrier + asm
      // clobber cannot order sunk register-only MFMAs / their lgkm waits).
      // vmcnt semantics identical to r7's asm at this point.
      __syncthreads();
    }
  }

  if (!FINAL) {
    // ---- coalesced z-write via LDS round-trip ----
    // lB[0]'s last readers were step 6, protected by the step-6 trailing
    // __syncthreads (full drain). Leading sync kept as defense-in-depth
    // (once per block, ~free).
    __syncthreads();
    ushort_t* Zt = (ushort_t*)lB[0];
#pragma unroll
    for (int mi = 0; mi < 2; ++mi)
#pragma unroll
      for (int r = 0; r < 4; ++r) {
        const int row = wm + mi * 16 + q * 4 + r;
        char* zrow = (char*)Zt + row * 256;
#pragma unroll
        for (int ni = 0; ni < 4; ++ni) {
          float v = acc[mi][ni][r];
          if (RELU) v = fmaxf(v, 0.0f);
          const int byte = ((wn + ni * 16 + fr) * 2) ^ ((row & 3) << 6);
          *(ushort_t*)(zrow + byte) = f2bf(v);
        }
      }
    __syncthreads();
    // read-back: thread -> (row = tid>>2, 16B slot = tid&3); 4 consecutive
    // tids fill one 64B line, quarter-wave fills 256B contiguous.
    {
      const int row = tid >> 2, sl = tid & 3;
      const char* zrow = (const char*)Zt + row * 256;
      ushort_t* gz = Z + (size_t)(zr0 + row) * H_DIM + bn0 + sl * 8;
#pragma unroll
      for (int j = 0; j < 4; ++j) {
        const ushort8 vv = *(const ushort8*)(
            zrow + ((j * 64 + sl * 16) ^ ((row & 3) << 6)));
        *(ushort8*)(gz + j * 32) = vv;
      }
    }
  } else {
    if (tid < 64) {
      wrow[tid] = wmap[zr0 + tid];
      rrow[tid] = rowmap[zr0 + tid];
    }
    __syncthreads();
#pragma unroll
    for (int mi = 0; mi < 2; ++mi)
#pragma unroll
      for (int r = 0; r < 4; ++r) {
        const int row = wm + mi * 16 + q * 4 + r;
        const float w = wrow[row];
        if (w != 0.0f) {
          const size_t orig = rrow[row];
#pragma unroll
          for (int ni = 0; ni < 4; ++ni) {
            const int col = bn0 + wn + ni * 16 + fr;
            if (col < T_DIM) {
              const float v = acc[mi][ni][r] * w;
              float* dst = (col < I_DIM)
                  ? out + orig * I_DIM + col
                  : out + (size_t)B_ROWS * I_DIM + orig * (T_DIM - I_DIM) +
                        (col - I_DIM);
              atomicAdd(dst, v);
            }
          }
        }
      }
  }
}

// ---------------------------------------------------------------- launch ----
extern "C" void kernel_launch(void* const* d_in, const int* in_sizes, int n_in,
                              void* d_out, int out_size, void* d_ws,
                              size_t ws_size, hipStream_t stream) {
  const float* x     = (const float*)d_in[0];
  const float* gamma = (const float*)d_in[1];
  const float* beta  = (const float*)d_in[2];
  const float* Wg    = (const float*)d_in[3];
  const float* W0    = (const float*)d_in[4];
  const float* Wmid  = (const float*)d_in[5];
  const float* Wout  = (const float*)d_in[6];
  float* out = (float*)d_out;

  char* ws = (char*)d_ws;
  size_t off = 0;
  auto alloc = [&](size_t bytes) -> char* {
    char* p = ws + off;
    off += (bytes + 255) & ~(size_t)255;
    return p;
  };

  const size_t SQ = (size_t)H_DIM * H_DIM;
  ushort_t* xb    = (ushort_t*)alloc((size_t)B_ROWS * I_DIM * 2);
  ushort_t* W0t   = (ushort_t*)alloc((size_t)E_NUM * SQ * 2);
  ushort_t* Wmidt = (ushort_t*)alloc((size_t)3 * E_NUM * SQ * 2);
  ushort_t* Woutt = (ushort_t*)alloc((size_t)E_NUM * T_PAD * H_DIM * 2);
  int2*   gidx  = (int2*)alloc((size_t)B_ROWS * sizeof(int2));
  float2* gwv   = (float2*)alloc((size_t)B_ROWS * sizeof(float2));
  int*   rmap   = (int*)alloc(NPAD * sizeof(int));
  float* wmap   = (float*)alloc(NPAD * sizeof(float));
  int*   cursor = (int*)alloc(E_NUM * sizeof(int));
  ushort_t* z0 = (ushort_t*)alloc((size_t)NPAD * H_DIM * 2);
  ushort_t* z1 = (ushort_t*)alloc((size_t)NPAD * H_DIM * 2);

  hipMemsetAsync(d_out, 0, (size_t)out_size * sizeof(float), stream);
  hipMemsetAsync(rmap, 0, NPAD * sizeof(int), stream);
  hipMemsetAsync(wmap, 0, NPAD * sizeof(float), stream);
  hipMemsetAsync(cursor, 0, E_NUM * sizeof(int), stream);

  gate_cast_k<<<dim3(B_ROWS / 4), 256, 0, stream>>>(x, gamma, beta, Wg, xb,
                                                    gidx, gwv);
  transpose_cast_k<<<dim3(16, 16, 8), dim3(32, 8), 0, stream>>>(
      W0, W0t, 512, 512, SQ, SQ);
  transpose_cast_k<<<dim3(16, 16, 24), dim3(32, 8), 0, stream>>>(
      Wmid, Wmidt, 512, 512, SQ, SQ);
  transpose_cast_k<<<dim3(19, 16, 8), dim3(32, 8), 0, stream>>>(
      Wout, Woutt, 512, 608, (size_t)512 * 608, (size_t)T_PAD * 512);
  assign_k<<<dim3(B_ROWS / 256), 256, 0, stream>>>(gidx, gwv, rmap, wmap,
                                                   cursor);

  const dim3 gmid(MT, H_DIM / 128);
  const dim3 gfin(MT, T_PAD / 128);
  // z0 = gather(x) @ W0   (no relu)
  gemm_k<true, false, false><<<gmid, 256, 0, stream>>>(
      xb, W0t, SQ, rmap, wmap, cursor, z0, nullptr);
  // z1 = relu(z0 @ Wmid[0])
  gemm_k<false, true, false><<<gmid, 256, 0, stream>>>(
      z0, Wmidt + 0 * E_NUM * SQ, SQ, rmap, wmap, cursor, z1, nullptr);
  // z0 = relu(z1 @ Wmid[1])
  gemm_k<false, true, false><<<gmid, 256, 0, stream>>>(
      z1, Wmidt + 1 * E_NUM * SQ, SQ, rmap, wmap, cursor, z0, nullptr);
  // z1 = relu(z0 @ Wmid[2])
  gemm_k<false, true, false><<<gmid, 256, 0, stream>>>(
      z0, Wmidt + 2 * E_NUM * SQ, SQ, rmap, wmap, cursor, z1, nullptr);
  // out += gate_w * (z1 @ Wout), scattered + split backcast/forecast
  gemm_k<false, false, true><<<gfin, 256, 0, stream>>>(
      z1, Woutt, (size_t)T_PAD * H_DIM, rmap, wmap, cursor, nullptr, out);
}